// Round 2
// baseline (1035.868 us; speedup 1.0000x reference)
//
#include <hip/hip_runtime.h>
#include <stdint.h>

// Problem constants: B=16, S=1024, D=512, H=8, HD=64
typedef unsigned short u16;
typedef __attribute__((ext_vector_type(8))) __bf16 bf16x8;
typedef __attribute__((ext_vector_type(8))) u16 u16x8;
typedef __attribute__((ext_vector_type(4))) float f32x4;

__device__ __forceinline__ u16 f2bf(float f) {
    unsigned u = __float_as_uint(f);
    u += 0x7fffu + ((u >> 16) & 1u);
    return (u16)(u >> 16);
}
__device__ __forceinline__ float bf2f(u16 h) {
    return __uint_as_float(((unsigned)h) << 16);
}

// ---------------- K0: convert Q -> bf16, W{q,k,v} -> bf16, row-valid mask ----
__global__ void k_prep(const float* __restrict__ Q,
                       const float* __restrict__ Wq, const float* __restrict__ Wk,
                       const float* __restrict__ Wv,
                       u16* __restrict__ qb, u16* __restrict__ wall,
                       float* __restrict__ fmask) {
    int bid = blockIdx.x;
    int t = threadIdx.x;  // 64 threads = 1 wave
    if (bid < 16384) {
        const float* src = Q + (size_t)bid * 512;
        u16* dst = qb + (size_t)bid * 512;
        float4 v0 = *(const float4*)(src + t * 4);
        float4 v1 = *(const float4*)(src + 256 + t * 4);
        bool nz = (v0.x != 0.f) || (v0.y != 0.f) || (v0.z != 0.f) || (v0.w != 0.f) ||
                  (v1.x != 0.f) || (v1.y != 0.f) || (v1.z != 0.f) || (v1.w != 0.f);
        ushort4 o0 = make_ushort4(f2bf(v0.x), f2bf(v0.y), f2bf(v0.z), f2bf(v0.w));
        ushort4 o1 = make_ushort4(f2bf(v1.x), f2bf(v1.y), f2bf(v1.z), f2bf(v1.w));
        *(ushort4*)(dst + t * 4) = o0;
        *(ushort4*)(dst + 256 + t * 4) = o1;
        unsigned long long bal = __ballot(nz);
        if (t == 0) fmask[bid] = bal ? 0.0f : -1e30f;
    } else {
        int r = bid - 16384;  // 0..1535
        const float* W = (r < 512) ? Wq : (r < 1024) ? Wk : Wv;
        const float* src = W + (size_t)(r & 511) * 512;
        u16* dst = wall + (size_t)r * 512;
        float4 v0 = *(const float4*)(src + t * 4);
        float4 v1 = *(const float4*)(src + 256 + t * 4);
        ushort4 o0 = make_ushort4(f2bf(v0.x), f2bf(v0.y), f2bf(v0.z), f2bf(v0.w));
        ushort4 o1 = make_ushort4(f2bf(v1.x), f2bf(v1.y), f2bf(v1.z), f2bf(v1.w));
        *(ushort4*)(dst + t * 4) = o0;
        *(ushort4*)(dst + 256 + t * 4) = o1;
    }
}

// ---------------- K1: fused QKV projection GEMM (BT form) -------------------
// C[m,n] = relu(sum_k qb[m,k]*wall[n,k] + bias[n]), M=16384, N=1536, K=512
// 128x128 tile, BK=32, 4 waves each computing a 64x64 quadrant (4x4 frags).
// Q/K outputs row-major bf16; V output written DIRECTLY TRANSPOSED into vT.
__global__ __launch_bounds__(256) void k_qkv(
        const u16* __restrict__ qb, const u16* __restrict__ wall,
        const float* __restrict__ bq, const float* __restrict__ bk,
        const float* __restrict__ bv,
        u16* __restrict__ oq, u16* __restrict__ ok, u16* __restrict__ vT) {
    __shared__ u16 As[128 * 32];
    __shared__ u16 Bs[128 * 32];
    int bm = blockIdx.x, bn = blockIdx.y;
    int tid = threadIdx.x, lane = tid & 63, wid = tid >> 6;
    int wm = wid >> 1, wn = wid & 1;
    int q4 = lane >> 4, l16 = lane & 15;

    f32x4 acc[4][4];
#pragma unroll
    for (int i = 0; i < 4; ++i)
#pragma unroll
        for (int j = 0; j < 4; ++j) acc[i][j] = (f32x4){0.f, 0.f, 0.f, 0.f};

#pragma unroll 1
    for (int kk = 0; kk < 16; ++kk) {
        float4 av[2], bw[2];
#pragma unroll
        for (int c = 0; c < 2; ++c) {
            int id = c * 256 + tid;
            int r = id >> 2, cb = (id & 3) * 8;
            av[c] = *(const float4*)(qb + ((size_t)(bm * 128 + r)) * 512 + kk * 32 + cb);
            bw[c] = *(const float4*)(wall + ((size_t)(bn * 128 + r)) * 512 + kk * 32 + cb);
        }
        __syncthreads();
#pragma unroll
        for (int c = 0; c < 2; ++c) {
            int id = c * 256 + tid;
            int r = id >> 2, cb = (id & 3) * 8;
            *(float4*)(&As[r * 32 + cb]) = av[c];
            *(float4*)(&Bs[r * 32 + cb]) = bw[c];
        }
        __syncthreads();
        bf16x8 af[4], bf[4];
#pragma unroll
        for (int i = 0; i < 4; ++i)
            af[i] = *(const bf16x8*)(&As[(wm * 64 + i * 16 + l16) * 32 + q4 * 8]);
#pragma unroll
        for (int j = 0; j < 4; ++j)
            bf[j] = *(const bf16x8*)(&Bs[(wn * 64 + j * 16 + l16) * 32 + q4 * 8]);
#pragma unroll
        for (int i = 0; i < 4; ++i)
#pragma unroll
            for (int j = 0; j < 4; ++j)
                acc[i][j] = __builtin_amdgcn_mfma_f32_16x16x32_bf16(af[i], bf[j], acc[i][j], 0, 0, 0);
    }

    int which = bn >> 2;  // 0=q 1=k 2=v
    if (which < 2) {
        const float* bias = (which == 0) ? bq : bk;
        u16* outp = (which == 0) ? oq : ok;
#pragma unroll
        for (int i = 0; i < 4; ++i)
#pragma unroll
            for (int j = 0; j < 4; ++j) {
                int n = bn * 128 + wn * 64 + j * 16 + l16;
                int c = n & 511;
                float bb = bias[c];
#pragma unroll
                for (int r = 0; r < 4; ++r) {
                    int m = bm * 128 + wm * 64 + i * 16 + q4 * 4 + r;
                    float val = acc[i][j][r] + bb;
                    val = fmaxf(val, 0.f);
                    outp[(size_t)m * 512 + c] = f2bf(val);
                }
            }
    } else {
        // transposed V store: lane holds 4 consecutive s-rows (q4*4+r) for col c
        size_t vrow0 = (size_t)(bm >> 3) * 512;
        int s0base = ((bm & 7) * 128) + wm * 64;
#pragma unroll
        for (int i = 0; i < 4; ++i)
#pragma unroll
            for (int j = 0; j < 4; ++j) {
                int c = (bn * 128 + wn * 64 + j * 16 + l16) & 511;
                float bb = bv[c];
                ushort4 o;
                o.x = f2bf(fmaxf(acc[i][j][0] + bb, 0.f));
                o.y = f2bf(fmaxf(acc[i][j][1] + bb, 0.f));
                o.z = f2bf(fmaxf(acc[i][j][2] + bb, 0.f));
                o.w = f2bf(fmaxf(acc[i][j][3] + bb, 0.f));
                int s0 = s0base + i * 16 + q4 * 4;
                *(ushort4*)(vT + (vrow0 + c) * 1024 + s0) = o;
            }
    }
}

// ---------------- K2: barrier-free single-pass-math attention ---------------
// No LDS staging of K/V: MFMA fragments are loaded directly from global
// (16 rows x 64B per access = coalesced; K/V head-slices are L2/L3-resident).
// Per wave: 16 q-rows, fully independent (no __syncthreads anywhere).
// Phase A: QK^T -> w'=exp(s) (shift-invariant softmax, no max) -> per-lane
//          row-sum accumulation; w' bf16 via per-wave 4KB LDS strip -> PV
//          accumulate with unnormalized w'.
// Phase B: recompute QK^T (cheap: L2-hot, no staging), store normalized fp32
//          weights (64B-contiguous segments per row).
// LDS total 17.4 KB; VGPR capped at 128 -> 4 waves/SIMD.
__global__ __launch_bounds__(256, 4) void k_attn(
        const u16* __restrict__ qv, const u16* __restrict__ kv,
        const u16* __restrict__ vT, const float* __restrict__ fmask,
        float* __restrict__ outAtt, float* __restrict__ outW) {
    __shared__ u16 Ws[4][16 * 136];

    int bid = blockIdx.x;
    int swz = ((bid & 7) << 8) | (bid >> 3);  // XCD-contiguous: 2048%8==0, bijective
    int qt = swz & 15, h = (swz >> 4) & 7, b = swz >> 7;
    int tid = threadIdx.x, lane = tid & 63, w = tid >> 6;
    int q4 = lane >> 4, l16 = lane & 15;
    const float scale = 0.125f;

    size_t qrow0 = (size_t)b * 1024 + qt * 64;
    size_t hc = (size_t)h * 64;
    size_t krowB = (size_t)b * 1024;
    u16* wsw = Ws[w];

    // Q fragments in registers (wave strip rows w*16 .. w*16+15)
    const u16* qp = qv + (qrow0 + w * 16 + l16) * 512 + hc;
    bf16x8 a0 = *(const bf16x8*)(qp + q4 * 8);
    bf16x8 a1 = *(const bf16x8*)(qp + 32 + q4 * 8);

    float qmv[4], lrun[4];
#pragma unroll
    for (int r = 0; r < 4; ++r) {
        qmv[r] = fmask[qrow0 + w * 16 + q4 * 4 + r];
        lrun[r] = 0.f;
    }
    f32x4 accO[4];
#pragma unroll
    for (int jn = 0; jn < 4; ++jn) accO[jn] = (f32x4){0.f, 0.f, 0.f, 0.f};

    const u16* vbase = vT + ((size_t)b * 512 + hc) * 1024;

    // ---------------- phase A: QK^T + exp + lsum + strip + PV ---------------
#pragma unroll 1
    for (int kt = 0; kt < 8; ++kt) {
        const u16* kbase = kv + (krowB + kt * 128) * 512 + hc;
        f32x4 acc[8];
        float km[8];
#pragma unroll
        for (int j = 0; j < 8; ++j) acc[j] = (f32x4){0.f, 0.f, 0.f, 0.f};
#pragma unroll
        for (int j = 0; j < 8; ++j) {
            const u16* kr = kbase + (size_t)(j * 16 + l16) * 512;
            bf16x8 b0 = *(const bf16x8*)(kr + q4 * 8);
            bf16x8 b1 = *(const bf16x8*)(kr + 32 + q4 * 8);
            km[j] = fmask[krowB + kt * 128 + j * 16 + l16];
            acc[j] = __builtin_amdgcn_mfma_f32_16x16x32_bf16(a0, b0, acc[j], 0, 0, 0);
            acc[j] = __builtin_amdgcn_mfma_f32_16x16x32_bf16(a1, b1, acc[j], 0, 0, 0);
        }
        // w' = exp(s); accumulate per-lane row sums; park bf16 in wave strip
#pragma unroll
        for (int j = 0; j < 8; ++j)
#pragma unroll
            for (int r = 0; r < 4; ++r) {
                float e = __expf(acc[j][r] * scale + qmv[r] + km[j]);
                lrun[r] += e;
                wsw[(q4 * 4 + r) * 136 + j * 16 + l16] = f2bf(e);
            }
        // PV with unnormalized w' (wave-local strip; compiler orders LDS ops)
        const u16* vkt = vbase + kt * 128;
#pragma unroll
        for (int ks = 0; ks < 4; ++ks) {
            bf16x8 aw = *(const bf16x8*)(&wsw[l16 * 136 + ks * 32 + q4 * 8]);
#pragma unroll
            for (int jn = 0; jn < 4; ++jn) {
                bf16x8 bvv = *(const bf16x8*)(vkt + (size_t)(jn * 16 + l16) * 1024 + ks * 32 + q4 * 8);
                accO[jn] = __builtin_amdgcn_mfma_f32_16x16x32_bf16(aw, bvv, accO[jn], 0, 0, 0);
            }
        }
    }

    // finalize l (single cross-lane reduce over the 16 key-column lanes)
    float rl[4];
#pragma unroll
    for (int r = 0; r < 4; ++r) {
        float s = lrun[r];
#pragma unroll
        for (int mm = 1; mm <= 8; mm <<= 1) s += __shfl_xor(s, mm, 64);
        rl[r] = (qmv[r] == 0.f && s > 0.f) ? (1.f / s) : 0.f;
    }

    // outAtt epilogue: scale accumulated PV, add residual
#pragma unroll
    for (int jn = 0; jn < 4; ++jn)
#pragma unroll
        for (int r = 0; r < 4; ++r) {
            int rowC = q4 * 4 + r;
            int hd = jn * 16 + l16;
            float qres = bf2f(qv[(qrow0 + w * 16 + rowC) * 512 + hc + hd]);
            outAtt[(qrow0 + w * 16 + rowC) * 512 + hc + hd] = accO[jn][r] * rl[r] + qres;
        }

    // ---------------- phase B: recompute QK^T, store normalized weights -----
    size_t wbase = ((size_t)(b * 8 + h)) * 1024 * 1024 + (size_t)(qt * 64 + w * 16) * 1024;
#pragma unroll 1
    for (int kt = 0; kt < 8; ++kt) {
        const u16* kbase = kv + (krowB + kt * 128) * 512 + hc;
        f32x4 acc[8];
        float km[8];
#pragma unroll
        for (int j = 0; j < 8; ++j) acc[j] = (f32x4){0.f, 0.f, 0.f, 0.f};
#pragma unroll
        for (int j = 0; j < 8; ++j) {
            const u16* kr = kbase + (size_t)(j * 16 + l16) * 512;
            bf16x8 b0 = *(const bf16x8*)(kr + q4 * 8);
            bf16x8 b1 = *(const bf16x8*)(kr + 32 + q4 * 8);
            km[j] = fmask[krowB + kt * 128 + j * 16 + l16];
            acc[j] = __builtin_amdgcn_mfma_f32_16x16x32_bf16(a0, b0, acc[j], 0, 0, 0);
            acc[j] = __builtin_amdgcn_mfma_f32_16x16x32_bf16(a1, b1, acc[j], 0, 0, 0);
        }
#pragma unroll
        for (int j = 0; j < 8; ++j)
#pragma unroll
            for (int r = 0; r < 4; ++r) {
                float e = __expf(acc[j][r] * scale + qmv[r] + km[j]) * rl[r];
                outW[wbase + (size_t)(q4 * 4 + r) * 1024 + kt * 128 + j * 16 + l16] = e;
            }
    }
}

// ---------------- K3: in-place LayerNorm + relu over D=512 ------------------
__global__ void k_ln(float* __restrict__ io, const float* __restrict__ lw,
                     const float* __restrict__ lb) {
    int row = blockIdx.x;
    int t = threadIdx.x;  // 64 threads = 1 wave
    float* p = io + (size_t)row * 512;
    float4 x0 = *(const float4*)(p + t * 4);
    float4 x1 = *(const float4*)(p + 256 + t * 4);
    float s = x0.x + x0.y + x0.z + x0.w + x1.x + x1.y + x1.z + x1.w;
    float s2 = x0.x * x0.x + x0.y * x0.y + x0.z * x0.z + x0.w * x0.w +
               x1.x * x1.x + x1.y * x1.y + x1.z * x1.z + x1.w * x1.w;
#pragma unroll
    for (int mm = 1; mm <= 32; mm <<= 1) {
        s += __shfl_xor(s, mm, 64);
        s2 += __shfl_xor(s2, mm, 64);
    }
    float mean = s * (1.f / 512.f);
    float var = s2 * (1.f / 512.f) - mean * mean;
    float inv = rsqrtf(var + 1e-5f);
    float4 w0 = *(const float4*)(lw + t * 4);
    float4 w1 = *(const float4*)(lw + 256 + t * 4);
    float4 b0 = *(const float4*)(lb + t * 4);
    float4 b1 = *(const float4*)(lb + 256 + t * 4);
    float4 o0, o1;
    o0.x = fmaxf((x0.x - mean) * inv * w0.x + b0.x, 0.f);
    o0.y = fmaxf((x0.y - mean) * inv * w0.y + b0.y, 0.f);
    o0.z = fmaxf((x0.z - mean) * inv * w0.z + b0.z, 0.f);
    o0.w = fmaxf((x0.w - mean) * inv * w0.w + b0.w, 0.f);
    o1.x = fmaxf((x1.x - mean) * inv * w1.x + b1.x, 0.f);
    o1.y = fmaxf((x1.y - mean) * inv * w1.y + b1.y, 0.f);
    o1.z = fmaxf((x1.z - mean) * inv * w1.z + b1.z, 0.f);
    o1.w = fmaxf((x1.w - mean) * inv * w1.w + b1.w, 0.f);
    *(float4*)(p + t * 4) = o0;
    *(float4*)(p + 256 + t * 4) = o1;
}

// ---------------- launcher --------------------------------------------------
extern "C" void kernel_launch(void* const* d_in, const int* in_sizes, int n_in,
                              void* d_out, int out_size, void* d_ws, size_t ws_size,
                              hipStream_t stream) {
    const float* Q = (const float*)d_in[0];
    const float* Wq_w = (const float*)d_in[1];
    const float* Wq_b = (const float*)d_in[2];
    const float* Wk_w = (const float*)d_in[3];
    const float* Wk_b = (const float*)d_in[4];
    const float* Wv_w = (const float*)d_in[5];
    const float* Wv_b = (const float*)d_in[6];
    const float* ln_w = (const float*)d_in[7];
    const float* ln_b = (const float*)d_in[8];

    // workspace layout (u16 element offsets)
    u16* ws16 = (u16*)d_ws;
    u16* qb   = ws16;                  // [16384][512] bf16
    u16* wall = ws16 + 8388608;        // [1536][512] bf16
    u16* oq   = ws16 + 9175040;        // [16384][512] bf16
    u16* okk  = ws16 + 17563648;       // [16384][512] bf16
    u16* vT   = ws16 + 25952256;       // [8192][1024] bf16 (V transposed)
    float* fmask = (float*)((char*)d_ws + 68681728);  // [16384] f32

    float* outAtt = (float*)d_out;               // [16,1024,512]
    float* outW = (float*)d_out + 8388608;       // [128,1024,1024]

    k_prep<<<17920, 64, 0, stream>>>(Q, Wq_w, Wk_w, Wv_w, qb, wall, fmask);
    k_qkv<<<dim3(128, 12), 256, 0, stream>>>(qb, wall, Wq_b, Wk_b, Wv_b, oq, okk, vT);
    k_attn<<<2048, 256, 0, stream>>>(oq, okk, vT, fmask, outAtt, outW);
    k_ln<<<16384, 64, 0, stream>>>(outAtt, ln_w, ln_b);
}